// Round 12
// baseline (7689.934 us; speedup 1.0000x reference)
//
#include <hip/hip_runtime.h>

// BiLSTM stacked: B=64 T=512 D=768 H=512 OUT=256
// lengths -> weight cvt -> xproj GEMMs (MFMA, fp16 gate storage) -> persistent
// flag-synced recurrence (r7 protocol; COARSENED: 512-thr blocks, 32 h-cols,
// 128KB weight LDS -> only 16 sync participants per direction) -> layer2 ->
// final GEMM. Workspace adapts to ws_size.

#define WS_B 64
#define WS_T 512
#define WS_D 768
#define WS_H 512
#define NTOK 32768  // B*T

typedef unsigned short u16;
typedef unsigned int u32;
typedef __attribute__((ext_vector_type(8))) short short8;   // 8 x bf16 MFMA frag
typedef __attribute__((ext_vector_type(4))) float f32x4;

__device__ __forceinline__ float bf2f(u16 u) {
    u32 x = ((u32)u) << 16;
    return __builtin_bit_cast(float, x);
}
__device__ __forceinline__ u16 f2bf(float f) {
    u32 x = __builtin_bit_cast(u32, f);
    u32 r = (x + 0x7FFFu + ((x >> 16) & 1u)) >> 16;  // RNE
    return (u16)r;
}
__device__ __forceinline__ float sigf(float x) {
    return __builtin_amdgcn_rcpf(1.0f + __builtin_amdgcn_exp2f(-1.4426950408889634f * x));
}
__device__ __forceinline__ float tanh_f(float x) {
    return 2.0f * __builtin_amdgcn_rcpf(1.0f + __builtin_amdgcn_exp2f(-2.8853900817779268f * x)) - 1.0f;
}
// write-through agent-coherent store (h publish; no L2 writeback needed)
__device__ __forceinline__ void cstore_u16(u16* p, u16 v) {
    __hip_atomic_store(p, v, __ATOMIC_RELAXED, __HIP_MEMORY_SCOPE_AGENT);
}

// ---------------- lengths: count of x[b,t,0] != 0 over t ----------------
__global__ void lengths_kernel(const float* __restrict__ x, int* __restrict__ len) {
    int b = blockIdx.x;
    float v = x[((size_t)b * WS_T + threadIdx.x) * WS_D];
    unsigned long long m = __ballot(v != 0.0f);
    __shared__ int part[8];
    if ((threadIdx.x & 63) == 0) part[threadIdx.x >> 6] = __popcll(m);
    __syncthreads();
    if (threadIdx.x == 0) {
        int s = 0;
        for (int i = 0; i < 8; ++i) s += part[i];
        len[b] = s;
    }
}

// ---------------- fp32 -> bf16 convert (vectorized x4) ----------------
__global__ void cvt_kernel(const float* __restrict__ s, u16* __restrict__ d, int n4) {
    int i = blockIdx.x * 256 + threadIdx.x;
    if (i >= n4) return;
    float4 v = ((const float4*)s)[i];
    ushort4 r;
    r.x = f2bf(v.x); r.y = f2bf(v.y); r.z = f2bf(v.z); r.w = f2bf(v.w);
    ((ushort4*)d)[i] = r;
}

// ---------------- in-place bf16 add: a += b (8 elems/thread) ----------------
__global__ void add_bf16_kernel(u16* __restrict__ a, const u16* __restrict__ b, int n8) {
    int i = blockIdx.x * 256 + threadIdx.x;
    if (i >= n8) return;
    ushort4 va0 = ((const ushort4*)a)[2 * i], va1 = ((const ushort4*)a)[2 * i + 1];
    ushort4 vb0 = ((const ushort4*)b)[2 * i], vb1 = ((const ushort4*)b)[2 * i + 1];
    ushort4 r0, r1;
    r0.x = f2bf(bf2f(va0.x) + bf2f(vb0.x)); r0.y = f2bf(bf2f(va0.y) + bf2f(vb0.y));
    r0.z = f2bf(bf2f(va0.z) + bf2f(vb0.z)); r0.w = f2bf(bf2f(va0.w) + bf2f(vb0.w));
    r1.x = f2bf(bf2f(va1.x) + bf2f(vb1.x)); r1.y = f2bf(bf2f(va1.y) + bf2f(vb1.y));
    r1.z = f2bf(bf2f(va1.z) + bf2f(vb1.z)); r1.w = f2bf(bf2f(va1.w) + bf2f(vb1.w));
    ((ushort4*)a)[2 * i] = r0; ((ushort4*)a)[2 * i + 1] = r1;
}

// ---------------- MFMA GEMM: C[M][N] = A[M][K] * W[N][K]^T + bias ----------------
// A32=1: A fp32, reg-staged with fused bf16 convert. A32=0: A bf16 via
// global_load_lds. W bf16 via global_load_lds. C stored as fp16.
#define BM 128
#define BN 128
#define BKT 64
template <int A32>
__global__ __launch_bounds__(256) void gemm_bt(
    const void* __restrict__ Av, const u16* __restrict__ W,
    const float* __restrict__ bias, _Float16* __restrict__ C,
    int M, int N, int K)
{
    __shared__ u16 As[BM * BKT];
    __shared__ u16 Bs[BN * BKT];
    const int tid = threadIdx.x;
    const int lane = tid & 63, w = tid >> 6;
    const int ntiles = N / BN;
    const int mt = blockIdx.x / ntiles, nt = blockIdx.x - mt * ntiles;
    const int m0 = mt * BM, n0 = nt * BN;
    const int wr = (w >> 1) * 64, wc = (w & 1) * 64;
    const int kin = (lane >> 4) << 4;  // byte offset of 8-elem group in 32-k step
    f32x4 acc[4][4] = {};
    for (int k0 = 0; k0 < K; k0 += BKT) {
#pragma unroll
        for (int it = 0; it < 4; ++it) {
            int off = it * 4096 + tid * 16;
            int row = off >> 7;
            int ce = (off & 127) >> 1;  // element col within 64-k tile
            const u16* gb = W + (size_t)(n0 + row) * K + (k0 + ce);
            char* lb = (char*)Bs + it * 4096 + w * 1024;  // wave-uniform base
            __builtin_amdgcn_global_load_lds(
                (const __attribute__((address_space(1))) u32*)gb,
                (__attribute__((address_space(3))) u32*)lb, 16, 0, 0);
            if constexpr (A32) {
                const float* ga = (const float*)Av + (size_t)(m0 + row) * K + (k0 + ce);
                float4 v0 = ((const float4*)ga)[0];
                float4 v1 = ((const float4*)ga)[1];
                u32 p0 = ((u32)f2bf(v0.y) << 16) | f2bf(v0.x);
                u32 p1 = ((u32)f2bf(v0.w) << 16) | f2bf(v0.z);
                u32 p2 = ((u32)f2bf(v1.y) << 16) | f2bf(v1.x);
                u32 p3 = ((u32)f2bf(v1.w) << 16) | f2bf(v1.z);
                *(uint4*)((char*)As + off) = make_uint4(p0, p1, p2, p3);
            } else {
                const u16* ga = (const u16*)Av + (size_t)(m0 + row) * K + (k0 + ce);
                char* la = (char*)As + it * 4096 + w * 1024;
                __builtin_amdgcn_global_load_lds(
                    (const __attribute__((address_space(1))) u32*)ga,
                    (__attribute__((address_space(3))) u32*)la, 16, 0, 0);
            }
        }
        asm volatile("s_waitcnt vmcnt(0)" ::: "memory");
        __syncthreads();
#pragma unroll
        for (int ks = 0; ks < 2; ++ks) {
            short8 av[4], bv[4];
#pragma unroll
            for (int mi = 0; mi < 4; ++mi)
                av[mi] = *(const short8*)((const char*)As + (wr + mi * 16 + (lane & 15)) * 128 + ks * 64 + kin);
#pragma unroll
            for (int ni = 0; ni < 4; ++ni)
                bv[ni] = *(const short8*)((const char*)Bs + (wc + ni * 16 + (lane & 15)) * 128 + ks * 64 + kin);
#pragma unroll
            for (int mi = 0; mi < 4; ++mi)
#pragma unroll
                for (int ni = 0; ni < 4; ++ni)
                    acc[mi][ni] = __builtin_amdgcn_mfma_f32_16x16x32_bf16(av[mi], bv[ni], acc[mi][ni], 0, 0, 0);
        }
        __syncthreads();
    }
    const int crow0 = m0 + wr + ((lane >> 4) << 2);
    const int ccol0 = n0 + wc + (lane & 15);
#pragma unroll
    for (int ni = 0; ni < 4; ++ni) {
        float bs = bias[ccol0 + ni * 16];
#pragma unroll
        for (int mi = 0; mi < 4; ++mi)
#pragma unroll
            for (int e = 0; e < 4; ++e)
                C[(size_t)(crow0 + mi * 16 + e) * N + (ccol0 + ni * 16)] =
                    (_Float16)(acc[mi][ni][e] + bs);
    }
}

// ---------------- persistent masked-LSTM recurrence (coarsened, r7 protocol) ----------------
// grid = 16 (one direction, dir0 selects) or 32 (both, blocks [16,32) = dir 1).
// Block: 512 threads (8 waves), owns 32 h-columns (128 gate rows); Whh slice
// (128 x 512 bf16 = 128KB) staged once into LDS. Wave (bg=w&3, ch=w>>2):
// batch rows [16bg,16bg+16), cols [hb_col+16ch, +16).
// h publish: write-through atomics -> barrier (vmcnt drain) -> tid0 RELEASE
// flag. Consume: relaxed spin over 16 flags -> barrier -> tid0 dummy ACQUIRE
// (single-wave inv) -> barrier -> cached vector loads. Aux after flag.
__global__ __launch_bounds__(512, 1) void lstm_rec(
    const u16* __restrict__ whhF, const u16* __restrict__ whhB,
    const _Float16* __restrict__ xgF, const _Float16* __restrict__ xgB,
    const int* __restrict__ lengths,
    u16* __restrict__ hb,      // this layer: [2 dir][2 buf][64][512] bf16
    float* __restrict__ hfin,  // this layer: [2 dir][64][512] f32
    u16* __restrict__ outF, u16* __restrict__ outB,  // [B*T][512] bf16
    int* __restrict__ flags,   // [n_dir_groups][32], zeroed (16 used)
    int writeOut, int dir0)
{
    __shared__ __align__(16) char wlds[131072];  // 128 frags x 64 lanes x 16B
    const int tid = threadIdx.x;
    const int lane = tid & 63, w = tid >> 6;     // 8 waves
    const int grp = blockIdx.x >> 4, wgl = blockIdx.x & 15;
    const int dir = dir0 + grp;
    const int hb_col = wgl << 5;                 // 32 cols per block
    const int ch = w >> 2;                       // column-half 0/1
    const int bg = w & 3;                        // batch group 0..3
    const u16* whh = dir ? whhB : whhF;
    const _Float16* xg = dir ? xgB : xgF;
    u16* outp = dir ? outB : outF;
    int* myflags = flags + (grp << 5);
    const int colL = lane & 15;
    const int hcol = hb_col + (ch << 4) + colL;
    const int qw = lane >> 4;            // quarter-wave 0..3
    const int arow = (bg << 4) + colL;   // A-frag batch row
    const int kofs = qw << 3;            // elem offset in 32-k step

    // stage Whh slice into LDS once: fragment f = kk*8 + g*2 + chf
    // at wlds[f*1024 + lane*16]; 8192 x 16B chunks over 512 threads
#pragma unroll
    for (int j = 0; j < 16; ++j) {
        int c = tid + j * 512;
        int f = c >> 6, lc = c & 63;
        int kk = f >> 3, g = (f >> 1) & 3, chf = f & 1;
        int R = (g << 9) + hb_col + (chf << 4) + (lc & 15);  // gate row in [0,2048)
        uint4 v = *(const uint4*)(whh + (size_t)R * WS_H + kk * 32 + ((lc >> 4) << 3));
        *(uint4*)(wlds + f * 1024 + lc * 16) = v;
    }
    int mylen[4], myb[4];
#pragma unroll
    for (int e = 0; e < 4; ++e) {
        myb[e] = (bg << 4) + (qw << 2) + e;
        mylen[e] = lengths[myb[e]];
    }
    float hreg[4] = {0.f, 0.f, 0.f, 0.f}, creg[4] = {0.f, 0.f, 0.f, 0.f};
    float xq[4][4];

    // prefetch gate pre-activations for step 0
#pragma unroll
    for (int e = 0; e < 4; ++e) {
        int len = mylen[e];
        int tx = dir ? (len - 1) : 0;
        int txc = tx < 0 ? 0 : (tx > 511 ? 511 : tx);
        const _Float16* xr = xg + ((size_t)(myb[e] * WS_T + txc) << 11);
        xq[e][0] = (float)xr[hcol];
        xq[e][1] = (float)xr[512 + hcol];
        xq[e][2] = (float)xr[1024 + hcol];
        xq[e][3] = (float)xr[1536 + hcol];
    }
    __syncthreads();  // weights staged

    for (int s = 0; s < WS_T; ++s) {
        const int pr = s & 1;
        const u16* hg = hb + (dir * 2 + pr) * 32768;
        u16* hw = hb + (dir * 2 + (pr ^ 1)) * 32768;

        // A-fragments: cached vectorized global->reg (fresh after acquire)
        short8 av[16];
#pragma unroll
        for (int kk = 0; kk < 16; ++kk)
            av[kk] = *(const short8*)(hg + arow * WS_H + kk * 32 + kofs);
        f32x4 acc[4] = {};
#pragma unroll
        for (int kk = 0; kk < 16; ++kk) {
            const char* wp = wlds + (((kk << 3) + ch) << 10) + lane * 16;
#pragma unroll
            for (int g = 0; g < 4; ++g) {
                short8 bg8 = *(const short8*)(wp + (g << 11));
                acc[g] = __builtin_amdgcn_mfma_f32_16x16x32_bf16(av[kk], bg8, acc[g], 0, 0, 0);
            }
        }

        // cell update (fp32 state in regs) + write-through h publish
#pragma unroll
        for (int e = 0; e < 4; ++e) {
            if (s < mylen[e]) {
                float gi = acc[0][e] + xq[e][0];
                float gf = acc[1][e] + xq[e][1];
                float gg = acc[2][e] + xq[e][2];
                float go = acc[3][e] + xq[e][3];
                float cn = sigf(gf) * creg[e] + sigf(gi) * tanh_f(gg);
                creg[e] = cn;
                hreg[e] = sigf(go) * tanh_f(cn);
            }
            cstore_u16(hw + myb[e] * WS_H + hcol, f2bf(hreg[e]));
        }
        __syncthreads();  // barrier waits vmcnt(0): h stores complete at L3
        if (tid == 0)
            __hip_atomic_store(&myflags[wgl], s + 1, __ATOMIC_RELEASE, __HIP_MEMORY_SCOPE_AGENT);

        // ---- off-critical-path: outputs, final h, next-step prefetch ----
        if (writeOut) {
#pragma unroll
            for (int e = 0; e < 4; ++e) {
                int len = mylen[e];
                int tx = dir ? (len - 1 - s) : s;
                if (s < len)
                    outp[((size_t)(myb[e] * WS_T + tx)) * 512 + hcol] = f2bf(hreg[e]);
            }
        }
        if (s == WS_T - 1) {
#pragma unroll
            for (int e = 0; e < 4; ++e)
                hfin[dir * 32768 + myb[e] * WS_H + hcol] = hreg[e];
        }
        if (s < WS_T - 1) {
#pragma unroll
            for (int e = 0; e < 4; ++e) {
                int len = mylen[e];
                int tx = dir ? (len - 2 - s) : (s + 1);
                int txc = tx < 0 ? 0 : (tx > 511 ? 511 : tx);
                const _Float16* xr = xg + ((size_t)(myb[e] * WS_T + txc) << 11);
                xq[e][0] = (float)xr[hcol];
                xq[e][1] = (float)xr[512 + hcol];
                xq[e][2] = (float)xr[1024 + hcol];
                xq[e][3] = (float)xr[1536 + hcol];
            }
            // relaxed spin: detect all 16 producers done with step s
            if (tid < 16) {
                while (__hip_atomic_load(&myflags[tid], __ATOMIC_RELAXED, __HIP_MEMORY_SCOPE_AGENT) <= s)
                    __builtin_amdgcn_s_sleep(1);
            }
            __syncthreads();
            // single acquire: one wave pays the vmcnt(0)+inv; barriers broadcast
            if (tid == 0) {
                int v = __hip_atomic_load(&myflags[0], __ATOMIC_ACQUIRE, __HIP_MEMORY_SCOPE_AGENT);
                asm volatile("" :: "v"(v));  // keep the acquire load live
            }
            __syncthreads();
        }
    }
}

// ---------------- final: out[b][o] = (h2f+h2b)[b] . W3[o] + b3[o] ----------------
__global__ void final_kernel(const float* __restrict__ hf, const float* __restrict__ hbk,
                             const float* __restrict__ W3, const float* __restrict__ b3,
                             float* __restrict__ out) {
    int b = blockIdx.x, o = threadIdx.x;
    __shared__ float h2[512];
    for (int k = threadIdx.x; k < 512; k += 256) h2[k] = hf[b * 512 + k] + hbk[b * 512 + k];
    __syncthreads();
    float s = b3[o];
#pragma unroll 8
    for (int k = 0; k < 512; ++k) s += h2[k] * W3[o * 512 + k];
    out[b * 256 + o] = s;
}

// ---------------- host ----------------
#define MB(x) ((size_t)(x) << 20)

extern "C" void kernel_launch(void* const* d_in, const int* in_sizes, int n_in,
                              void* d_out, int out_size, void* d_ws, size_t ws_size,
                              hipStream_t stream) {
    (void)in_sizes; (void)n_in; (void)out_size;
    const float* x      = (const float*)d_in[0];
    const float* b1f    = (const float*)d_in[3];
    const float* b1b    = (const float*)d_in[6];
    const float* b2f    = (const float*)d_in[9];
    const float* b2b    = (const float*)d_in[12];
    const float* W3     = (const float*)d_in[13];
    const float* b3     = (const float*)d_in[14];
    float* out = (float*)d_out;
    char* ws = (char*)d_ws;

    // control block
    enum : size_t {
        O_LEN  = 0,          // 256 B
        O_FLG  = 512,        // 4 regions x 128B (32 ints each; 16 used)
        O_HB1  = 4096,       // [2][2][64][512] bf16 = 256 KB
        O_HB2  = O_HB1 + 262144,
        O_HF1  = O_HB2 + 262144,   // [2][64][512] f32 = 256 KB
        O_HF2  = O_HF1 + 262144,
        O_CTRL_END = O_HF2 + 262144
    };
    const size_t O_W1FH = MB(2),  O_W1BH = MB(4),  O_W2FH = MB(6),  O_W2BH = MB(8);
    const size_t O_W1FI = MB(10), O_W1BI = MB(13), O_W2FI = MB(16), O_W2BI = MB(18);
    const size_t O_OUTF = MB(20), O_OUTB = MB(52);
    const size_t O_XG0  = MB(84), O_XG1  = MB(212);
    const size_t NEED_SEQ = MB(212), NEED_PAR = MB(340);
    if (ws_size < NEED_SEQ) return;  // cannot run: fail validation cleanly
    const bool par = ws_size >= NEED_PAR;

    (void)hipMemsetAsync(ws, 0, O_CTRL_END, stream);
    (void)hipMemsetAsync(ws + O_OUTF, 0, MB(64), stream);

    int* lenp = (int*)(ws + O_LEN);
    lengths_kernel<<<64, 512, 0, stream>>>(x, lenp);

    // weight bf16 conversions
    cvt_kernel<<<1024, 256, 0, stream>>>((const float*)d_in[2],  (u16*)(ws + O_W1FH), 262144);
    cvt_kernel<<<1024, 256, 0, stream>>>((const float*)d_in[5],  (u16*)(ws + O_W1BH), 262144);
    cvt_kernel<<<1024, 256, 0, stream>>>((const float*)d_in[8],  (u16*)(ws + O_W2FH), 262144);
    cvt_kernel<<<1024, 256, 0, stream>>>((const float*)d_in[11], (u16*)(ws + O_W2BH), 262144);
    cvt_kernel<<<1536, 256, 0, stream>>>((const float*)d_in[1],  (u16*)(ws + O_W1FI), 393216);
    cvt_kernel<<<1536, 256, 0, stream>>>((const float*)d_in[4],  (u16*)(ws + O_W1BI), 393216);
    cvt_kernel<<<1024, 256, 0, stream>>>((const float*)d_in[7],  (u16*)(ws + O_W2FI), 262144);
    cvt_kernel<<<1024, 256, 0, stream>>>((const float*)d_in[10], (u16*)(ws + O_W2BI), 262144);

    _Float16* xg0 = (_Float16*)(ws + O_XG0);
    _Float16* xg1 = par ? (_Float16*)(ws + O_XG1) : xg0;
    u16* outFp = (u16*)(ws + O_OUTF);
    u16* outBp = (u16*)(ws + O_OUTB);

    if (par) {
        // ---- layer 1 ----
        gemm_bt<1><<<4096, 256, 0, stream>>>(x, (u16*)(ws + O_W1FI), b1f, xg0, NTOK, 2048, 768);
        gemm_bt<1><<<4096, 256, 0, stream>>>(x, (u16*)(ws + O_W1BI), b1b, xg1, NTOK, 2048, 768);
        lstm_rec<<<32, 512, 0, stream>>>((u16*)(ws + O_W1FH), (u16*)(ws + O_W1BH),
                                         xg0, xg1, lenp,
                                         (u16*)(ws + O_HB1), (float*)(ws + O_HF1),
                                         outFp, outBp, (int*)(ws + O_FLG), 1, 0);
        add_bf16_kernel<<<8192, 256, 0, stream>>>(outFp, outBp, 2097152);
        // ---- layer 2 ----
        gemm_bt<0><<<4096, 256, 0, stream>>>(outFp, (u16*)(ws + O_W2FI), b2f, xg0, NTOK, 2048, 512);
        gemm_bt<0><<<4096, 256, 0, stream>>>(outFp, (u16*)(ws + O_W2BI), b2b, xg1, NTOK, 2048, 512);
        lstm_rec<<<32, 512, 0, stream>>>((u16*)(ws + O_W2FH), (u16*)(ws + O_W2BH),
                                         xg0, xg1, lenp,
                                         (u16*)(ws + O_HB2), (float*)(ws + O_HF2),
                                         outFp, outBp, (int*)(ws + O_FLG + 512), 0, 0);
    } else {
        // ---- layer 1, forward then backward, sharing xg0 ----
        gemm_bt<1><<<4096, 256, 0, stream>>>(x, (u16*)(ws + O_W1FI), b1f, xg0, NTOK, 2048, 768);
        lstm_rec<<<16, 512, 0, stream>>>((u16*)(ws + O_W1FH), (u16*)(ws + O_W1FH),
                                         xg0, xg0, lenp,
                                         (u16*)(ws + O_HB1), (float*)(ws + O_HF1),
                                         outFp, outBp, (int*)(ws + O_FLG), 1, 0);
        gemm_bt<1><<<4096, 256, 0, stream>>>(x, (u16*)(ws + O_W1BI), b1b, xg0, NTOK, 2048, 768);
        lstm_rec<<<16, 512, 0, stream>>>((u16*)(ws + O_W1BH), (u16*)(ws + O_W1BH),
                                         xg0, xg0, lenp,
                                         (u16*)(ws + O_HB1), (float*)(ws + O_HF1),
                                         outFp, outBp, (int*)(ws + O_FLG + 256), 1, 1);
        add_bf16_kernel<<<8192, 256, 0, stream>>>(outFp, outBp, 2097152);
        // ---- layer 2 ----
        gemm_bt<0><<<4096, 256, 0, stream>>>(outFp, (u16*)(ws + O_W2FI), b2f, xg0, NTOK, 2048, 512);
        lstm_rec<<<16, 512, 0, stream>>>((u16*)(ws + O_W2FH), (u16*)(ws + O_W2FH),
                                         xg0, xg0, lenp,
                                         (u16*)(ws + O_HB2), (float*)(ws + O_HF2),
                                         outFp, outBp, (int*)(ws + O_FLG + 512), 0, 0);
        gemm_bt<0><<<4096, 256, 0, stream>>>(outFp, (u16*)(ws + O_W2BI), b2b, xg0, NTOK, 2048, 512);
        lstm_rec<<<16, 512, 0, stream>>>((u16*)(ws + O_W2BH), (u16*)(ws + O_W2BH),
                                         xg0, xg0, lenp,
                                         (u16*)(ws + O_HB2), (float*)(ws + O_HF2),
                                         outFp, outBp, (int*)(ws + O_FLG + 768), 0, 1);
    }
    final_kernel<<<64, 256, 0, stream>>>((const float*)(ws + O_HF2),
                                         (const float*)(ws + O_HF2) + 32768, W3, b3, out);
}

// Round 14
// 5928.197 us; speedup vs baseline: 1.2972x; 1.2972x over previous
//
#include <hip/hip_runtime.h>

// BiLSTM stacked: B=64 T=512 D=768 H=512 OUT=256
// lengths -> weight cvt -> xproj GEMMs (MFMA, fp16 gate storage) -> persistent
// flag-synced recurrence (r7 protocol, minus RELEASE-writeback and one
// barrier: Whh in LDS; h publish = write-through atomics + barrier drain +
// RELAXED flag; consume = xq prefetch + relaxed spin -> tid0 dummy ACQUIRE
// (single-wave inv) -> ONE barrier -> cached vector loads) -> layer2 -> final.

#define WS_B 64
#define WS_T 512
#define WS_D 768
#define WS_H 512
#define NTOK 32768  // B*T

typedef unsigned short u16;
typedef unsigned int u32;
typedef __attribute__((ext_vector_type(8))) short short8;   // 8 x bf16 MFMA frag
typedef __attribute__((ext_vector_type(4))) float f32x4;

__device__ __forceinline__ float bf2f(u16 u) {
    u32 x = ((u32)u) << 16;
    return __builtin_bit_cast(float, x);
}
__device__ __forceinline__ u16 f2bf(float f) {
    u32 x = __builtin_bit_cast(u32, f);
    u32 r = (x + 0x7FFFu + ((x >> 16) & 1u)) >> 16;  // RNE
    return (u16)r;
}
__device__ __forceinline__ float sigf(float x) {
    return __builtin_amdgcn_rcpf(1.0f + __builtin_amdgcn_exp2f(-1.4426950408889634f * x));
}
__device__ __forceinline__ float tanh_f(float x) {
    return 2.0f * __builtin_amdgcn_rcpf(1.0f + __builtin_amdgcn_exp2f(-2.8853900817779268f * x)) - 1.0f;
}
// write-through agent-coherent store (h publish; no L2 writeback needed)
__device__ __forceinline__ void cstore_u16(u16* p, u16 v) {
    __hip_atomic_store(p, v, __ATOMIC_RELAXED, __HIP_MEMORY_SCOPE_AGENT);
}

// ---------------- lengths: count of x[b,t,0] != 0 over t ----------------
__global__ void lengths_kernel(const float* __restrict__ x, int* __restrict__ len) {
    int b = blockIdx.x;
    float v = x[((size_t)b * WS_T + threadIdx.x) * WS_D];
    unsigned long long m = __ballot(v != 0.0f);
    __shared__ int part[8];
    if ((threadIdx.x & 63) == 0) part[threadIdx.x >> 6] = __popcll(m);
    __syncthreads();
    if (threadIdx.x == 0) {
        int s = 0;
        for (int i = 0; i < 8; ++i) s += part[i];
        len[b] = s;
    }
}

// ---------------- fp32 -> bf16 convert (vectorized x4) ----------------
__global__ void cvt_kernel(const float* __restrict__ s, u16* __restrict__ d, int n4) {
    int i = blockIdx.x * 256 + threadIdx.x;
    if (i >= n4) return;
    float4 v = ((const float4*)s)[i];
    ushort4 r;
    r.x = f2bf(v.x); r.y = f2bf(v.y); r.z = f2bf(v.z); r.w = f2bf(v.w);
    ((ushort4*)d)[i] = r;
}

// ---------------- in-place bf16 add: a += b (8 elems/thread) ----------------
__global__ void add_bf16_kernel(u16* __restrict__ a, const u16* __restrict__ b, int n8) {
    int i = blockIdx.x * 256 + threadIdx.x;
    if (i >= n8) return;
    ushort4 va0 = ((const ushort4*)a)[2 * i], va1 = ((const ushort4*)a)[2 * i + 1];
    ushort4 vb0 = ((const ushort4*)b)[2 * i], vb1 = ((const ushort4*)b)[2 * i + 1];
    ushort4 r0, r1;
    r0.x = f2bf(bf2f(va0.x) + bf2f(vb0.x)); r0.y = f2bf(bf2f(va0.y) + bf2f(vb0.y));
    r0.z = f2bf(bf2f(va0.z) + bf2f(vb0.z)); r0.w = f2bf(bf2f(va0.w) + bf2f(vb0.w));
    r1.x = f2bf(bf2f(va1.x) + bf2f(vb1.x)); r1.y = f2bf(bf2f(va1.y) + bf2f(vb1.y));
    r1.z = f2bf(bf2f(va1.z) + bf2f(vb1.z)); r1.w = f2bf(bf2f(va1.w) + bf2f(vb1.w));
    ((ushort4*)a)[2 * i] = r0; ((ushort4*)a)[2 * i + 1] = r1;
}

// ---------------- MFMA GEMM: C[M][N] = A[M][K] * W[N][K]^T + bias ----------------
// A32=1: A fp32, reg-staged with fused bf16 convert. A32=0: A bf16 via
// global_load_lds. W bf16 via global_load_lds. C stored as fp16.
#define BM 128
#define BN 128
#define BKT 64
template <int A32>
__global__ __launch_bounds__(256) void gemm_bt(
    const void* __restrict__ Av, const u16* __restrict__ W,
    const float* __restrict__ bias, _Float16* __restrict__ C,
    int M, int N, int K)
{
    __shared__ u16 As[BM * BKT];
    __shared__ u16 Bs[BN * BKT];
    const int tid = threadIdx.x;
    const int lane = tid & 63, w = tid >> 6;
    const int ntiles = N / BN;
    const int mt = blockIdx.x / ntiles, nt = blockIdx.x - mt * ntiles;
    const int m0 = mt * BM, n0 = nt * BN;
    const int wr = (w >> 1) * 64, wc = (w & 1) * 64;
    const int kin = (lane >> 4) << 4;  // byte offset of 8-elem group in 32-k step
    f32x4 acc[4][4] = {};
    for (int k0 = 0; k0 < K; k0 += BKT) {
#pragma unroll
        for (int it = 0; it < 4; ++it) {
            int off = it * 4096 + tid * 16;
            int row = off >> 7;
            int ce = (off & 127) >> 1;  // element col within 64-k tile
            const u16* gb = W + (size_t)(n0 + row) * K + (k0 + ce);
            char* lb = (char*)Bs + it * 4096 + w * 1024;  // wave-uniform base
            __builtin_amdgcn_global_load_lds(
                (const __attribute__((address_space(1))) u32*)gb,
                (__attribute__((address_space(3))) u32*)lb, 16, 0, 0);
            if constexpr (A32) {
                const float* ga = (const float*)Av + (size_t)(m0 + row) * K + (k0 + ce);
                float4 v0 = ((const float4*)ga)[0];
                float4 v1 = ((const float4*)ga)[1];
                u32 p0 = ((u32)f2bf(v0.y) << 16) | f2bf(v0.x);
                u32 p1 = ((u32)f2bf(v0.w) << 16) | f2bf(v0.z);
                u32 p2 = ((u32)f2bf(v1.y) << 16) | f2bf(v1.x);
                u32 p3 = ((u32)f2bf(v1.w) << 16) | f2bf(v1.z);
                *(uint4*)((char*)As + off) = make_uint4(p0, p1, p2, p3);
            } else {
                const u16* ga = (const u16*)Av + (size_t)(m0 + row) * K + (k0 + ce);
                char* la = (char*)As + it * 4096 + w * 1024;
                __builtin_amdgcn_global_load_lds(
                    (const __attribute__((address_space(1))) u32*)ga,
                    (__attribute__((address_space(3))) u32*)la, 16, 0, 0);
            }
        }
        asm volatile("s_waitcnt vmcnt(0)" ::: "memory");
        __syncthreads();
#pragma unroll
        for (int ks = 0; ks < 2; ++ks) {
            short8 av[4], bv[4];
#pragma unroll
            for (int mi = 0; mi < 4; ++mi)
                av[mi] = *(const short8*)((const char*)As + (wr + mi * 16 + (lane & 15)) * 128 + ks * 64 + kin);
#pragma unroll
            for (int ni = 0; ni < 4; ++ni)
                bv[ni] = *(const short8*)((const char*)Bs + (wc + ni * 16 + (lane & 15)) * 128 + ks * 64 + kin);
#pragma unroll
            for (int mi = 0; mi < 4; ++mi)
#pragma unroll
                for (int ni = 0; ni < 4; ++ni)
                    acc[mi][ni] = __builtin_amdgcn_mfma_f32_16x16x32_bf16(av[mi], bv[ni], acc[mi][ni], 0, 0, 0);
        }
        __syncthreads();
    }
    const int crow0 = m0 + wr + ((lane >> 4) << 2);
    const int ccol0 = n0 + wc + (lane & 15);
#pragma unroll
    for (int ni = 0; ni < 4; ++ni) {
        float bs = bias[ccol0 + ni * 16];
#pragma unroll
        for (int mi = 0; mi < 4; ++mi)
#pragma unroll
            for (int e = 0; e < 4; ++e)
                C[(size_t)(crow0 + mi * 16 + e) * N + (ccol0 + ni * 16)] =
                    (_Float16)(acc[mi][ni][e] + bs);
    }
}

// ---------------- persistent masked-LSTM recurrence ----------------
// grid = 32 (one direction, dir0 selects) or 64 (both, blocks [32,64) = dir 1).
// Block owns 16 h-columns (64 gate rows); Whh slice staged once into LDS.
// h publish: write-through agent atomics -> barrier (vmcnt drain) -> tid0
// RELAXED flag (no wbl2). h consume: xq prefetch -> relaxed spin (wave0) ->
// tid0 dummy ACQUIRE load (load+inv) -> ONE barrier -> cached vector loads.
__global__ __launch_bounds__(256, 1) void lstm_rec(
    const u16* __restrict__ whhF, const u16* __restrict__ whhB,
    const _Float16* __restrict__ xgF, const _Float16* __restrict__ xgB,
    const int* __restrict__ lengths,
    u16* __restrict__ hb,      // this layer: [2 dir][2 buf][64][512] bf16
    float* __restrict__ hfin,  // this layer: [2 dir][64][512] f32
    u16* __restrict__ outF, u16* __restrict__ outB,  // [B*T][512] bf16
    int* __restrict__ flags,   // [n_dir_groups][32], zeroed
    int writeOut, int dir0)
{
    __shared__ __align__(16) char wlds[65536];  // 64 B-fragments x 64 lanes x 16B
    const int tid = threadIdx.x;
    const int lane = tid & 63, w = tid >> 6;
    const int grp = blockIdx.x >> 5, wgl = blockIdx.x & 31;
    const int dir = dir0 + grp;
    const int hb_col = wgl << 4;
    const u16* whh = dir ? whhB : whhF;
    const _Float16* xg = dir ? xgB : xgF;
    u16* outp = dir ? outB : outF;
    int* myflags = flags + (grp << 5);
    const int colL = lane & 15;
    const int hcol = hb_col + colL;
    const int qw = lane >> 4;           // quarter-wave 0..3
    const int arow = (w << 4) + colL;   // A-frag batch row
    const int kofs = qw << 3;           // elem offset in 32-k step

    // stage Whh slice into LDS once: fragment f=kk*4+g at wlds[f*1024 + lane*16]
#pragma unroll
    for (int j = 0; j < 16; ++j) {
        int f = (w << 4) + j, kk = f >> 2, g = f & 3;
        int R = (g << 9) + hb_col + colL;  // gate row in [0,2048)
        uint4 v = *(const uint4*)(whh + (size_t)R * WS_H + kk * 32 + kofs);
        *(uint4*)(wlds + f * 1024 + lane * 16) = v;
    }
    int mylen[4], myb[4];
#pragma unroll
    for (int e = 0; e < 4; ++e) {
        myb[e] = (w << 4) + (qw << 2) + e;
        mylen[e] = lengths[myb[e]];
    }
    float hreg[4] = {0.f, 0.f, 0.f, 0.f}, creg[4] = {0.f, 0.f, 0.f, 0.f};
    float xq[4][4];

    // prefetch gate pre-activations for step 0
#pragma unroll
    for (int e = 0; e < 4; ++e) {
        int len = mylen[e];
        int tx = dir ? (len - 1) : 0;
        int txc = tx < 0 ? 0 : (tx > 511 ? 511 : tx);
        const _Float16* xr = xg + ((size_t)(myb[e] * WS_T + txc) << 11);
        xq[e][0] = (float)xr[hcol];
        xq[e][1] = (float)xr[512 + hcol];
        xq[e][2] = (float)xr[1024 + hcol];
        xq[e][3] = (float)xr[1536 + hcol];
    }
    __syncthreads();  // weights staged

    for (int s = 0; s < WS_T; ++s) {
        const int pr = s & 1;
        const u16* hg = hb + (dir * 2 + pr) * 32768;
        u16* hw = hb + (dir * 2 + (pr ^ 1)) * 32768;

        // A-fragments: cached vectorized global->reg (L2 was invalidated after
        // the flag spin, so these read fresh data from L3)
        short8 av[16];
#pragma unroll
        for (int kk = 0; kk < 16; ++kk)
            av[kk] = *(const short8*)(hg + arow * WS_H + kk * 32 + kofs);
        f32x4 acc[4] = {};
#pragma unroll
        for (int kk = 0; kk < 16; ++kk) {
            const char* wp = wlds + (kk << 12) + lane * 16;
#pragma unroll
            for (int g = 0; g < 4; ++g) {
                short8 bg = *(const short8*)(wp + (g << 10));
                acc[g] = __builtin_amdgcn_mfma_f32_16x16x32_bf16(av[kk], bg, acc[g], 0, 0, 0);
            }
        }

        // cell update (fp32 state in regs) + write-through h publish
#pragma unroll
        for (int e = 0; e < 4; ++e) {
            if (s < mylen[e]) {
                float gi = acc[0][e] + xq[e][0];
                float gf = acc[1][e] + xq[e][1];
                float gg = acc[2][e] + xq[e][2];
                float go = acc[3][e] + xq[e][3];
                float cn = sigf(gf) * creg[e] + sigf(gi) * tanh_f(gg);
                creg[e] = cn;
                hreg[e] = sigf(go) * tanh_f(cn);
            }
            cstore_u16(hw + myb[e] * WS_H + hcol, f2bf(hreg[e]));
        }
        __syncthreads();  // barrier waits vmcnt(0): h stores complete at L3
        if (tid == 0)
            __hip_atomic_store(&myflags[wgl], s + 1, __ATOMIC_RELAXED, __HIP_MEMORY_SCOPE_AGENT);

        // ---- off-critical-path: outputs, final h, next-step prefetch ----
        if (writeOut) {
#pragma unroll
            for (int e = 0; e < 4; ++e) {
                int len = mylen[e];
                int tx = dir ? (len - 1 - s) : s;
                if (s < len)
                    outp[((size_t)(myb[e] * WS_T + tx)) * 512 + hcol] = f2bf(hreg[e]);
            }
        }
        if (s == WS_T - 1) {
#pragma unroll
            for (int e = 0; e < 4; ++e)
                hfin[dir * 32768 + myb[e] * WS_H + hcol] = hreg[e];
        }
        if (s < WS_T - 1) {
            // prefetch gate pre-activations for step s+1
#pragma unroll
            for (int e = 0; e < 4; ++e) {
                int len = mylen[e];
                int tx = dir ? (len - 2 - s) : (s + 1);
                int txc = tx < 0 ? 0 : (tx > 511 ? 511 : tx);
                const _Float16* xr = xg + ((size_t)(myb[e] * WS_T + txc) << 11);
                xq[e][0] = (float)xr[hcol];
                xq[e][1] = (float)xr[512 + hcol];
                xq[e][2] = (float)xr[1024 + hcol];
                xq[e][3] = (float)xr[1536 + hcol];
            }
            // relaxed spin (wave0): detect all 32 producers done with step s
            if (tid < 32) {
                while (__hip_atomic_load(&myflags[tid], __ATOMIC_RELAXED, __HIP_MEMORY_SCOPE_AGENT) <= s)
                    __builtin_amdgcn_s_sleep(1);
            }
            // single acquire by tid0 (same wave as the spin): load + inv;
            // barrier orders all waves behind the completed invalidate
            if (tid == 0) {
                int v = __hip_atomic_load(&myflags[0], __ATOMIC_ACQUIRE, __HIP_MEMORY_SCOPE_AGENT);
                asm volatile("" :: "v"(v));  // keep the acquire load live
            }
            __syncthreads();
        }
    }
}

// ---------------- final: out[b][o] = (h2f+h2b)[b] . W3[o] + b3[o] ----------------
__global__ void final_kernel(const float* __restrict__ hf, const float* __restrict__ hbk,
                             const float* __restrict__ W3, const float* __restrict__ b3,
                             float* __restrict__ out) {
    int b = blockIdx.x, o = threadIdx.x;
    __shared__ float h2[512];
    for (int k = threadIdx.x; k < 512; k += 256) h2[k] = hf[b * 512 + k] + hbk[b * 512 + k];
    __syncthreads();
    float s = b3[o];
#pragma unroll 8
    for (int k = 0; k < 512; ++k) s += h2[k] * W3[o * 512 + k];
    out[b * 256 + o] = s;
}

// ---------------- host ----------------
#define MB(x) ((size_t)(x) << 20)

extern "C" void kernel_launch(void* const* d_in, const int* in_sizes, int n_in,
                              void* d_out, int out_size, void* d_ws, size_t ws_size,
                              hipStream_t stream) {
    (void)in_sizes; (void)n_in; (void)out_size;
    const float* x      = (const float*)d_in[0];
    const float* b1f    = (const float*)d_in[3];
    const float* b1b    = (const float*)d_in[6];
    const float* b2f    = (const float*)d_in[9];
    const float* b2b    = (const float*)d_in[12];
    const float* W3     = (const float*)d_in[13];
    const float* b3     = (const float*)d_in[14];
    float* out = (float*)d_out;
    char* ws = (char*)d_ws;

    // control block
    enum : size_t {
        O_LEN  = 0,          // 256 B
        O_FLG  = 512,        // 4 regions
        O_HB1  = 4096,       // [2][2][64][512] bf16 = 256 KB
        O_HB2  = O_HB1 + 262144,
        O_HF1  = O_HB2 + 262144,   // [2][64][512] f32 = 256 KB
        O_HF2  = O_HF1 + 262144,
        O_CTRL_END = O_HF2 + 262144
    };
    const size_t O_W1FH = MB(2),  O_W1BH = MB(4),  O_W2FH = MB(6),  O_W2BH = MB(8);
    const size_t O_W1FI = MB(10), O_W1BI = MB(13), O_W2FI = MB(16), O_W2BI = MB(18);
    const size_t O_OUTF = MB(20), O_OUTB = MB(52);
    const size_t O_XG0  = MB(84), O_XG1  = MB(212);
    const size_t NEED_SEQ = MB(212), NEED_PAR = MB(340);
    if (ws_size < NEED_SEQ) return;  // cannot run: fail validation cleanly
    const bool par = ws_size >= NEED_PAR;

    (void)hipMemsetAsync(ws, 0, O_CTRL_END, stream);
    (void)hipMemsetAsync(ws + O_OUTF, 0, MB(64), stream);

    int* lenp = (int*)(ws + O_LEN);
    lengths_kernel<<<64, 512, 0, stream>>>(x, lenp);

    // weight bf16 conversions
    cvt_kernel<<<1024, 256, 0, stream>>>((const float*)d_in[2],  (u16*)(ws + O_W1FH), 262144);
    cvt_kernel<<<1024, 256, 0, stream>>>((const float*)d_in[5],  (u16*)(ws + O_W1BH), 262144);
    cvt_kernel<<<1024, 256, 0, stream>>>((const float*)d_in[8],  (u16*)(ws + O_W2FH), 262144);
    cvt_kernel<<<1024, 256, 0, stream>>>((const float*)d_in[11], (u16*)(ws + O_W2BH), 262144);
    cvt_kernel<<<1536, 256, 0, stream>>>((const float*)d_in[1],  (u16*)(ws + O_W1FI), 393216);
    cvt_kernel<<<1536, 256, 0, stream>>>((const float*)d_in[4],  (u16*)(ws + O_W1BI), 393216);
    cvt_kernel<<<1024, 256, 0, stream>>>((const float*)d_in[7],  (u16*)(ws + O_W2FI), 262144);
    cvt_kernel<<<1024, 256, 0, stream>>>((const float*)d_in[10], (u16*)(ws + O_W2BI), 262144);

    _Float16* xg0 = (_Float16*)(ws + O_XG0);
    _Float16* xg1 = par ? (_Float16*)(ws + O_XG1) : xg0;
    u16* outFp = (u16*)(ws + O_OUTF);
    u16* outBp = (u16*)(ws + O_OUTB);

    if (par) {
        // ---- layer 1 ----
        gemm_bt<1><<<4096, 256, 0, stream>>>(x, (u16*)(ws + O_W1FI), b1f, xg0, NTOK, 2048, 768);
        gemm_bt<1><<<4096, 256, 0, stream>>>(x, (u16*)(ws + O_W1BI), b1b, xg1, NTOK, 2048, 768);
        lstm_rec<<<64, 256, 0, stream>>>((u16*)(ws + O_W1FH), (u16*)(ws + O_W1BH),
                                         xg0, xg1, lenp,
                                         (u16*)(ws + O_HB1), (float*)(ws + O_HF1),
                                         outFp, outBp, (int*)(ws + O_FLG), 1, 0);
        add_bf16_kernel<<<8192, 256, 0, stream>>>(outFp, outBp, 2097152);
        // ---- layer 2 ----
        gemm_bt<0><<<4096, 256, 0, stream>>>(outFp, (u16*)(ws + O_W2FI), b2f, xg0, NTOK, 2048, 512);
        gemm_bt<0><<<4096, 256, 0, stream>>>(outFp, (u16*)(ws + O_W2BI), b2b, xg1, NTOK, 2048, 512);
        lstm_rec<<<64, 256, 0, stream>>>((u16*)(ws + O_W2FH), (u16*)(ws + O_W2BH),
                                         xg0, xg1, lenp,
                                         (u16*)(ws + O_HB2), (float*)(ws + O_HF2),
                                         outFp, outBp, (int*)(ws + O_FLG + 512), 0, 0);
    } else {
        // ---- layer 1, forward then backward, sharing xg0 ----
        gemm_bt<1><<<4096, 256, 0, stream>>>(x, (u16*)(ws + O_W1FI), b1f, xg0, NTOK, 2048, 768);
        lstm_rec<<<32, 256, 0, stream>>>((u16*)(ws + O_W1FH), (u16*)(ws + O_W1FH),
                                         xg0, xg0, lenp,
                                         (u16*)(ws + O_HB1), (float*)(ws + O_HF1),
                                         outFp, outBp, (int*)(ws + O_FLG), 1, 0);
        gemm_bt<1><<<4096, 256, 0, stream>>>(x, (u16*)(ws + O_W1BI), b1b, xg0, NTOK, 2048, 768);
        lstm_rec<<<32, 256, 0, stream>>>((u16*)(ws + O_W1BH), (u16*)(ws + O_W1BH),
                                         xg0, xg0, lenp,
                                         (u16*)(ws + O_HB1), (float*)(ws + O_HF1),
                                         outFp, outBp, (int*)(ws + O_FLG + 256), 1, 1);
        add_bf16_kernel<<<8192, 256, 0, stream>>>(outFp, outBp, 2097152);
        // ---- layer 2 ----
        gemm_bt<0><<<4096, 256, 0, stream>>>(outFp, (u16*)(ws + O_W2FI), b2f, xg0, NTOK, 2048, 512);
        lstm_rec<<<32, 256, 0, stream>>>((u16*)(ws + O_W2FH), (u16*)(ws + O_W2FH),
                                         xg0, xg0, lenp,
                                         (u16*)(ws + O_HB2), (float*)(ws + O_HF2),
                                         outFp, outBp, (int*)(ws + O_FLG + 512), 0, 0);
        gemm_bt<0><<<4096, 256, 0, stream>>>(outFp, (u16*)(ws + O_W2BI), b2b, xg0, NTOK, 2048, 512);
        lstm_rec<<<32, 256, 0, stream>>>((u16*)(ws + O_W2BH), (u16*)(ws + O_W2BH),
                                         xg0, xg0, lenp,
                                         (u16*)(ws + O_HB2), (float*)(ws + O_HF2),
                                         outFp, outBp, (int*)(ws + O_FLG + 768), 0, 1);
    }
    final_kernel<<<64, 256, 0, stream>>>((const float*)(ws + O_HF2),
                                         (const float*)(ws + O_HF2) + 32768, W3, b3, out);
}